// Round 3
// baseline (2298.802 us; speedup 1.0000x reference)
//
#include <hip/hip_runtime.h>
#include <math.h>

// Problem constants (match reference)
#define NB   32
#define NA   24564
#define NTOT (NB * NA)          // 786048 = 128 * 6141 exactly
#define NCH  85                 // 4 box deltas + 81 logits
#define TOPK 200
#define IOU_THR_F     0.5f
#define SCORE_FLOOR_F 0.01f

#define DEC_T 128               // decode block size (exact divisor of NTOT)
#define NMS_T 512               // nms block size
#define SLOTS ((NA + NMS_T - 1) / NMS_T)   // 48 anchors per thread
#define KPASS 8                 // winners selected per pass
#define NPOOL (2 * NMS_T)       // 1024 candidate entries (top-2 per thread)
// entry e lives at cache slot (e&15) of lane (e>>4); LDS addr transposed so
// the per-pass cache load is lane-contiguous (coalesced, 2-way bank = free)
#define CKADDR(e) ((((e) & 15) << 6) | ((e) >> 4))

// ---------------------------------------------------------------------------
// Kernel 1: decode boxes + softmax score/cls per anchor.
// LDS-staged coalesced input; per-thread arithmetic BIT-IDENTICAL to the
// R1-passing version (strict __f*_rn, exp in double). DO NOT alter numerics.
// ---------------------------------------------------------------------------
__global__ __launch_bounds__(DEC_T) void decode_kernel(
    const float* __restrict__ x, const float* __restrict__ anchor,
    float4* __restrict__ boxes, float* __restrict__ scores,
    float* __restrict__ clsf)
{
    __shared__ float tile[DEC_T * NCH];            // 43,520 B -> 3 blocks/CU

    const int base = blockIdx.x * DEC_T;
    const float4* src = (const float4*)(x + (size_t)base * NCH);
    float4* dst = (float4*)tile;
    for (int k = threadIdx.x; k < DEC_T * NCH / 4; k += DEC_T) dst[k] = src[k];
    __syncthreads();

    const int g = base + threadIdx.x;
    const int i = g % NA;
    const float* row = tile + threadIdx.x * NCH;

    float ax = anchor[i * 4 + 0];
    float ay = anchor[i * 4 + 1];
    float aw = anchor[i * 4 + 2];
    float ah = anchor[i * 4 + 3];

    float d0 = row[0], d1 = row[1], d2 = row[2], d3 = row[3];
    float cx = __fadd_rn(__fdiv_rn(__fmul_rn(d0, aw), 10.0f), ax);
    float cy = __fadd_rn(__fdiv_rn(__fmul_rn(d1, ah), 10.0f), ay);
    float w = __fmul_rn((float)exp((double)__fdiv_rn(d2, 5.0f)), aw);
    float h = __fmul_rn((float)exp((double)__fdiv_rn(d3, 5.0f)), ah);
    float hw = __fmul_rn(w, 0.5f);
    float hh = __fmul_rn(h, 0.5f);
    boxes[g] = make_float4(__fsub_rn(cx, hw), __fsub_rn(cy, hh),
                           __fadd_rn(cx, hw), __fadd_rn(cy, hh));

    const float* z = row + 4;
    float m = z[0];
    #pragma unroll 9
    for (int k = 1; k < 81; k++) m = fmaxf(m, z[k]);

    double S = 0.0;
    double be = 0.0;
    float  bz = -INFINITY;
    int    bj = 0;
    for (int k = 0; k < 81; k++) {
        float zk = z[k];
        double e = exp((double)__fsub_rn(zk, m));
        S += e;
        if (k >= 1 && zk > bz) { bz = zk; be = e; bj = k - 1; }
    }
    scores[g] = (float)(be / S);
    clsf[g]   = (float)bj;
}

// ---------------------------------------------------------------------------
// IoU suppression predicate — EXACT op sequence of the reference:
//   areas precomputed with the same __fmul_rn(__fsub_rn...) ops, clip extents
//   to [0,1], denom = (a1+a2)-common, correctly-rounded division, suppress on
//   !(iou < 0.5) (NaN suppresses). DO NOT replace the division with an
//   algebraic compare (1-ulp flips).
// v/a2 = candidate box/area, w/a1 = winner box/area (ref: box1 = winner).
// ---------------------------------------------------------------------------
__device__ __forceinline__ bool suppressed_by(const float4 v, const float a2,
                                              const float4 w, const float a1)
{
    float xl = fmaxf(w.x, v.x);
    float xr = fminf(w.z, v.z);
    float yt = fmaxf(w.y, v.y);
    float yb = fminf(w.w, v.w);
    float cw  = fminf(fmaxf(__fsub_rn(xr, xl), 0.0f), 1.0f);
    float chh = fminf(fmaxf(__fsub_rn(yb, yt), 0.0f), 1.0f);
    float common = __fmul_rn(cw, chh);
    float denom  = __fsub_rn(__fadd_rn(a1, a2), common);
    float iou    = __fdiv_rn(common, denom);
    return !(iou < IOU_THR_F);
}

// ---------------------------------------------------------------------------
// wave64 u32-max reduce via DPP (row_shr 1/2/4/8 + row_bcast 15/31 -> lane
// 63 holds the max), then v_readlane 63 -> SGPR (wave-uniform result).
// ~6 VALU-latency stages (~60-90 cy) vs ~700+ cy for a u64 ds-shuffle
// butterfly — this was the R2 selection-loop latency bottleneck.
// bound_ctrl=false + old=x: invalid source lanes keep their own value (max
// identity). All 64 lanes active at every call site (uniform control flow).
// ---------------------------------------------------------------------------
__device__ __forceinline__ unsigned wave_umax_dpp(unsigned v)
{
    int x = (int)v;
    #define DPP_ST(C) { \
        int y_ = __builtin_amdgcn_update_dpp(x, x, C, 0xF, 0xF, false); \
        x = ((unsigned)y_ > (unsigned)x) ? y_ : x; }
    DPP_ST(0x111)   // row_shr:1
    DPP_ST(0x112)   // row_shr:2
    DPP_ST(0x114)   // row_shr:4
    DPP_ST(0x118)   // row_shr:8  -> lanes 15/31/47/63 hold row maxes
    DPP_ST(0x142)   // row_bcast:15 -> lane63 = max(row3,row2); lane31 = max(r1,r0)
    DPP_ST(0x143)   // row_bcast:31 -> lane63 = max(all)
    #undef DPP_ST
    return (unsigned)__builtin_amdgcn_readlane(x, 63);
}

// ---------------------------------------------------------------------------
// Kernel 2: per-batch greedy NMS, K=8 winners per pass (EAGER suppression).
//
// R1 lesson: lazy repair = serial dependent-latency chain, 5x WORSE.
// R2 lesson: pass structure good (1555 from 2018), but (a) box[48] spilled
//   to scratch (VGPR demand: 192 box + 32 u64-cache + 56 winner arrays >
//   256) -> 12.5 MB scratch writes + per-pass scratch rescans; (b) the u64
//   __shfl_xor butterfly (12 dependent ds_bpermute, ~700cy) dominated each
//   selection iteration. This version:
//   - winner pass-state in LDS (s_pw*, lane0-written; all waves compute
//     identical values so same-value writes are benign) — no winner regs.
//   - key cache split to 16xu32 score + 16xu32 lo (16 VGPRs, was 32).
//     Peak regs ~ 192 + 16 + temps < 256 -> box stays resident.
//   - selection max via 2-phase DPP+readlane (score max, then packed-lo max
//     among score-ties). Result lands in SGPRs -> scalar control flow.
//     Order = (score, NA-j) exactly; entry-id bits sit below NA-j (unique)
//     so they never decide a comparison.
//   - consume/hbound via readlane (uniform lane index), no shfl.
//   - kill sweep loop-swapped: winner-outer (one LDS broadcast read), slot
//     inner static (box[] register-indexed).
// hbound invariant (unchanged from R2): hidden (3rd+) boxes of a thread are
// strictly below its 2nd-best published key; consumes happen in strictly
// decreasing key order, so the SECOND consume of a pair bounds that thread's
// hidden boxes. Pass ends when pool-max <= hbound. First selection of a pass
// always succeeds -> guaranteed progress.
//
// __launch_bounds__(512, 1) is LOAD-BEARING (256-VGPR budget at 2 waves/SIMD).
// CRITICAL (R2 bug): winner is killed EXPLICITLY by index — ref IoU clips
// intersection extents to [0,1] but not areas, so self-IoU can be < 0.5.
// ---------------------------------------------------------------------------
__global__ __launch_bounds__(NMS_T, 1) void nms_kernel(
    const float4* __restrict__ boxes, const float* __restrict__ scores,
    const float* __restrict__ clsf, float* __restrict__ out)
{
    __shared__ float s_score[NA];                  // 98,256 B (own-slot reads)
    __shared__ unsigned s_cs[NPOOL];               //  4,096 B key hi (score bits)
    __shared__ unsigned s_cl[NPOOL];               //  4,096 B key lo ((NA-j)<<10|e)
    __shared__ float4 s_cbox[NPOOL];               // 16,384 B candidate boxes
    __shared__ float4 s_pwbox[KPASS];              // pass-winner boxes
    __shared__ float  s_pwarea[KPASS];
    __shared__ float  s_pwscore[KPASS];
    __shared__ int    s_pwj[KPASS];

    const int b    = blockIdx.x;
    const int tid  = threadIdx.x;
    const int lane = tid & 63;
    const float*  sc = scores + (size_t)b * NA;
    const float4* bx = boxes  + (size_t)b * NA;
    const float*  cf = clsf   + (size_t)b * NA;
    float* ob = out + (size_t)b * TOPK * 6;

    float4 box[SLOTS];
    unsigned long long alive = 0ULL;
    #pragma unroll
    for (int s = 0; s < SLOTS; s++) {
        int j = tid + s * NMS_T;
        box[s] = make_float4(0.0f, 0.0f, 0.0f, 0.0f);
        if (j < NA) { box[s] = bx[j]; alive |= (1ULL << s); }
    }
    for (int j = tid; j < NA; j += NMS_T) s_score[j] = sc[j];

    int t = 0; bool gdone = false;

    // ---- initial top-2 publish (no winners yet)
    {
        unsigned long long k1 = 0ULL, k2 = 0ULL; int j1 = -1, j2 = -1;
        #pragma unroll
        for (int s = 0; s < SLOTS; s++) {
            if (!(alive & (1ULL << s))) continue;
            int j = tid + s * NMS_T;
            unsigned long long kk =
                ((unsigned long long)__float_as_uint(s_score[j]) << 32) |
                ((unsigned long long)(unsigned)(NA - j) << 10);
            if (kk > k1)      { k2 = k1; j2 = j1; k1 = kk; j1 = j; }
            else if (kk > k2) { k2 = kk; j2 = j; }
        }
        int e0 = 2 * tid, e1 = 2 * tid + 1;
        s_cs[CKADDR(e0)] = (j1 >= 0) ? (unsigned)(k1 >> 32) : 1u;
        s_cl[CKADDR(e0)] = (unsigned)k1 | (unsigned)e0;
        s_cs[CKADDR(e1)] = (j2 >= 0) ? (unsigned)(k2 >> 32) : 1u;
        s_cl[CKADDR(e1)] = (unsigned)k2 | (unsigned)e1;
        if (j1 >= 0) s_cbox[e0] = bx[j1];
        if (j2 >= 0) s_cbox[e1] = bx[j2];
    }
    __syncthreads();

    while (true) {
        // ---- cache pool keys: lane L owns entries [L*16, L*16+16)
        unsigned cs[16], cl[16];
        #pragma unroll
        for (int i = 0; i < 16; i++) {
            cs[i] = s_cs[(i << 6) | lane];
            cl[i] = s_cl[(i << 6) | lane];
        }

        // ---- selection (all waves redundantly; deterministic-identical)
        int npass = 0;
        unsigned long long hbound = 0ULL;
        int kmax = TOPK - t; if (kmax > KPASS) kmax = KPASS;
        while (true) {
            // phase 1: wave-max score
            unsigned msl = 0u;
            #pragma unroll
            for (int i = 0; i < 16; i++) msl = (cs[i] > msl) ? cs[i] : msl;
            unsigned ms = wave_umax_dpp(msl);              // uniform (SGPR)
            // phase 2: wave-max packed lo among score ties
            unsigned lol = 0u;
            #pragma unroll
            for (int i = 0; i < 16; i++)
                if (cs[i] == ms) lol = (cl[i] > lol) ? cl[i] : lol;
            unsigned lo = wave_umax_dpp(lol);              // uniform (SGPR)
            unsigned long long lm = ((unsigned long long)ms << 32) | lo;

            // hbound check FIRST (a hidden 3rd-best may outrank the floor-fail)
            if (!(lm > hbound)) break;                     // end pass, rescan
            float msf = __uint_as_float(ms);
            if (!(msf >= SCORE_FLOOR_F)) { gdone = true; break; }

            int e  = (int)(lo & 1023u);
            int jw = NA - (int)((lo >> 10) & 0x7FFFu);
            float4 cb = s_cbox[e];                         // uniform broadcast
            float  ca = __fmul_rn(__fsub_rn(cb.z, cb.x), __fsub_rn(cb.w, cb.y));

            bool kill = false;
            for (int k = 0; k < npass; k++) {              // uniform trip count
                float4 wb = s_pwbox[k];
                kill |= suppressed_by(cb, ca, wb, s_pwarea[k]);
            }

            // consume entry e; second-of-pair consume raises hbound
            int olane = e >> 4, oi = e & 15;               // uniform scalars
            unsigned pks = 0u;
            #pragma unroll
            for (int i = 0; i < 16; i++) if (i == (oi ^ 1)) pks = cs[i];
            unsigned pkol = (unsigned)__builtin_amdgcn_readlane((int)pks, olane);
            if (pkol == 0u) hbound = lm;                   // lm > hbound here
            bool me = (lane == olane);
            #pragma unroll
            for (int i = 0; i < 16; i++) if (i == oi && me) cs[i] = 0u;

            if (!kill) {
                if (lane == 0) {                           // same-value across waves
                    s_pwbox[npass]   = cb;
                    s_pwarea[npass]  = ca;
                    s_pwscore[npass] = msf;
                    s_pwj[npass]     = jw;
                }
                npass++;
                if (npass == kmax) break;
            }
        }

        // ---- emit winners (owner thread writes row; cls via 1 global load)
        for (int k = 0; k < npass; k++) {
            int jw = s_pwj[k];                             // uniform broadcast
            if (tid == (jw & (NMS_T - 1))) {
                float4 wb = s_pwbox[k];
                float* o6 = ob + (size_t)(t + k) * 6;
                o6[0] = cf[jw];
                o6[1] = s_pwscore[k];
                o6[2] = wb.x; o6[3] = wb.y; o6[4] = wb.z; o6[5] = wb.w;
            }
        }
        t += npass;
        if (gdone || t >= TOPK) break;

        __syncthreads();   // B1: all waves done reading pool before republish

        // ---- explicit winner self-kills (by index)
        for (int k = 0; k < npass; k++) {
            int jw = s_pwj[k];
            if (tid == (jw & (NMS_T - 1))) alive &= ~(1ULL << (jw >> 9));
        }
        // ---- kill sweep: winner-outer (LDS broadcast), slot-inner static
        for (int k = 0; k < npass; k++) {
            float4 wb = s_pwbox[k];
            float  wa = s_pwarea[k];
            #pragma unroll
            for (int s = 0; s < SLOTS; s++) {
                if (alive & (1ULL << s)) {
                    float4 v = box[s];
                    float a2 = __fmul_rn(__fsub_rn(v.z, v.x),
                                         __fsub_rn(v.w, v.y));
                    if (suppressed_by(v, a2, wb, wa)) alive &= ~(1ULL << s);
                }
            }
        }
        // ---- top-2 rescan + republish
        {
            unsigned long long k1 = 0ULL, k2 = 0ULL; int j1 = -1, j2 = -1;
            #pragma unroll
            for (int s = 0; s < SLOTS; s++) {
                if (!(alive & (1ULL << s))) continue;
                int j = tid + s * NMS_T;
                unsigned long long kk =
                    ((unsigned long long)__float_as_uint(s_score[j]) << 32) |
                    ((unsigned long long)(unsigned)(NA - j) << 10);
                if (kk > k1)      { k2 = k1; j2 = j1; k1 = kk; j1 = j; }
                else if (kk > k2) { k2 = kk; j2 = j; }
            }
            int e0 = 2 * tid, e1 = 2 * tid + 1;
            s_cs[CKADDR(e0)] = (j1 >= 0) ? (unsigned)(k1 >> 32) : 1u;
            s_cl[CKADDR(e0)] = (unsigned)k1 | (unsigned)e0;
            s_cs[CKADDR(e1)] = (j2 >= 0) ? (unsigned)(k2 >> 32) : 1u;
            s_cl[CKADDR(e1)] = (unsigned)k2 | (unsigned)e1;
            if (j1 >= 0) s_cbox[e0] = bx[j1];   // L2-resident reload
            if (j2 >= 0) s_cbox[e1] = bx[j2];
        }
        __syncthreads();   // B2: republish visible before next key-cache load
    }

    for (int k = t * 6 + tid; k < TOPK * 6; k += NMS_T) ob[k] = 0.0f;
}

// ---------------------------------------------------------------------------
extern "C" void kernel_launch(void* const* d_in, const int* in_sizes, int n_in,
                              void* d_out, int out_size, void* d_ws, size_t ws_size,
                              hipStream_t stream) {
    const float* x      = (const float*)d_in[0];   // (32, 24564, 85)
    const float* anchor = (const float*)d_in[1];   // (24564, 4)
    float* out = (float*)d_out;                    // (32, 200, 6)

    char* ws = (char*)d_ws;
    const size_t boxes_bytes  = (size_t)NTOT * 16;
    const size_t scores_off   = (boxes_bytes + 255) & ~255ULL;
    const size_t scores_bytes = (size_t)NTOT * 4;
    const size_t cls_off      = (scores_off + scores_bytes + 255) & ~255ULL;

    float4* boxes  = (float4*)ws;
    float*  scores = (float*)(ws + scores_off);
    float*  clsf   = (float*)(ws + cls_off);

    decode_kernel<<<NTOT / DEC_T, DEC_T, 0, stream>>>(x, anchor, boxes, scores, clsf);
    nms_kernel<<<NB, NMS_T, 0, stream>>>(boxes, scores, clsf, out);
}

// Round 7
// 2211.092 us; speedup vs baseline: 1.0397x; 1.0397x over previous
//
#include <hip/hip_runtime.h>
#include <math.h>

// Problem constants (match reference)
#define NB   32
#define NA   24564
#define NTOT (NB * NA)          // 786048 = 128 * 6141 exactly
#define NCH  85                 // 4 box deltas + 81 logits
#define TOPK 200
#define IOU_THR_F     0.5f
#define SCORE_FLOOR_F 0.01f

#define DEC_T 128               // decode block size (exact divisor of NTOT)
#define NMS_T 512               // nms block size
#define SLOTS ((NA + NMS_T - 1) / NMS_T)   // 48 anchors per thread
#define KPASS 8                 // winners selected per pass
#define NPOOL (2 * NMS_T)       // 1024 candidate entries (top-2 per thread)
// transposed key layout so each lane's 16 cached entries spread banks
#define CKADDR(e) ((((e) & 15) << 6) | ((e) >> 4))

// ---------------------------------------------------------------------------
// Kernel 1: decode boxes + softmax score/cls per anchor.
// LDS-staged coalesced input; per-thread arithmetic BIT-IDENTICAL to the
// R1-passing version (strict __f*_rn, exp in double). DO NOT alter numerics.
// ---------------------------------------------------------------------------
__global__ __launch_bounds__(DEC_T) void decode_kernel(
    const float* __restrict__ x, const float* __restrict__ anchor,
    float4* __restrict__ boxes, float* __restrict__ scores,
    float* __restrict__ clsf)
{
    __shared__ float tile[DEC_T * NCH];            // 43,520 B -> 3 blocks/CU

    const int base = blockIdx.x * DEC_T;
    const float4* src = (const float4*)(x + (size_t)base * NCH);
    float4* dst = (float4*)tile;
    for (int k = threadIdx.x; k < DEC_T * NCH / 4; k += DEC_T) dst[k] = src[k];
    __syncthreads();

    const int g = base + threadIdx.x;
    const int i = g % NA;
    const float* row = tile + threadIdx.x * NCH;

    float ax = anchor[i * 4 + 0];
    float ay = anchor[i * 4 + 1];
    float aw = anchor[i * 4 + 2];
    float ah = anchor[i * 4 + 3];

    float d0 = row[0], d1 = row[1], d2 = row[2], d3 = row[3];
    float cx = __fadd_rn(__fdiv_rn(__fmul_rn(d0, aw), 10.0f), ax);
    float cy = __fadd_rn(__fdiv_rn(__fmul_rn(d1, ah), 10.0f), ay);
    float w = __fmul_rn((float)exp((double)__fdiv_rn(d2, 5.0f)), aw);
    float h = __fmul_rn((float)exp((double)__fdiv_rn(d3, 5.0f)), ah);
    float hw = __fmul_rn(w, 0.5f);
    float hh = __fmul_rn(h, 0.5f);
    boxes[g] = make_float4(__fsub_rn(cx, hw), __fsub_rn(cy, hh),
                           __fadd_rn(cx, hw), __fadd_rn(cy, hh));

    const float* z = row + 4;
    float m = z[0];
    #pragma unroll 9
    for (int k = 1; k < 81; k++) m = fmaxf(m, z[k]);

    double S = 0.0;
    double be = 0.0;
    float  bz = -INFINITY;
    int    bj = 0;
    for (int k = 0; k < 81; k++) {
        float zk = z[k];
        double e = exp((double)__fsub_rn(zk, m));
        S += e;
        if (k >= 1 && zk > bz) { bz = zk; be = e; bj = k - 1; }
    }
    scores[g] = (float)(be / S);
    clsf[g]   = (float)bj;
}

// ---------------------------------------------------------------------------
// IoU suppression predicate — EXACT op sequence of the reference:
//   areas precomputed with the same __fmul_rn(__fsub_rn...) ops, clip extents
//   to [0,1], denom = (a1+a2)-common, correctly-rounded division, suppress on
//   !(iou < 0.5) (NaN suppresses). DO NOT replace the division with an
//   algebraic compare (1-ulp flips).
// v/a2 = candidate box/area, w/a1 = winner box/area (ref: box1 = winner).
// ---------------------------------------------------------------------------
__device__ __forceinline__ bool suppressed_by(const float4 v, const float a2,
                                              const float4 w, const float a1)
{
    float xl = fmaxf(w.x, v.x);
    float xr = fminf(w.z, v.z);
    float yt = fmaxf(w.y, v.y);
    float yb = fminf(w.w, v.w);
    float cw  = fminf(fmaxf(__fsub_rn(xr, xl), 0.0f), 1.0f);
    float chh = fminf(fmaxf(__fsub_rn(yb, yt), 0.0f), 1.0f);
    float common = __fmul_rn(cw, chh);
    float denom  = __fsub_rn(__fadd_rn(a1, a2), common);
    float iou    = __fdiv_rn(common, denom);
    return !(iou < IOU_THR_F);
}

// Fast-path variant for the fused sweep ONLY. For FINITE inputs (provable:
// normals/uniforms/exp/softmax — no NaN/Inf reachable) this is BIT-EXACT:
// reject-true => xr-xl<=0 or yb-yt<=0 => cw==0 or chh==0 => common==0 =>
// iou = 0/denom = 0 < 0.5 => not suppressed. Saves the clip+mul+div on the
// (majority) non-overlapping pairs.
__device__ __forceinline__ bool suppressed_by_fast(const float4 v, const float a2,
                                                   const float4 w, const float a1)
{
    float xl = fmaxf(w.x, v.x);
    float xr = fminf(w.z, v.z);
    float yt = fmaxf(w.y, v.y);
    float yb = fminf(w.w, v.w);
    if (xr <= xl || yb <= yt) return false;       // zero intersection
    float cw  = fminf(fmaxf(__fsub_rn(xr, xl), 0.0f), 1.0f);
    float chh = fminf(fmaxf(__fsub_rn(yb, yt), 0.0f), 1.0f);
    float common = __fmul_rn(cw, chh);
    float denom  = __fsub_rn(__fadd_rn(a1, a2), common);
    float iou    = __fdiv_rn(common, denom);
    return !(iou < IOU_THR_F);
}

// ---------------------------------------------------------------------------
// wave64 u32-max reduce via DPP (row_shr 1/2/4/8 + row_bcast 15/31 -> lane
// 63 holds the max), then v_readlane 63 -> SGPR (wave-uniform result).
// Hardware-verified in R3 (passed harness). ~6 VALU stages vs ~500-700cy of
// dependent ds_bpermute for the u64 shuffle butterfly it replaces.
// ---------------------------------------------------------------------------
__device__ __forceinline__ unsigned wave_umax_dpp(unsigned v)
{
    int x = (int)v;
    #define DPP_ST(C) { \
        int y_ = __builtin_amdgcn_update_dpp(x, x, C, 0xF, 0xF, false); \
        x = ((unsigned)y_ > (unsigned)x) ? y_ : x; }
    DPP_ST(0x111)   // row_shr:1
    DPP_ST(0x112)   // row_shr:2
    DPP_ST(0x114)   // row_shr:4
    DPP_ST(0x118)   // row_shr:8  -> lanes 15/31/47/63 hold row maxes
    DPP_ST(0x142)   // row_bcast:15
    DPP_ST(0x143)   // row_bcast:31 -> lane63 = max(all)
    #undef DPP_ST
    return (unsigned)__builtin_amdgcn_readlane(x, 63);
}

// ---------------------------------------------------------------------------
// Kernel 2: per-batch greedy NMS, K=8 winners per pass (EAGER suppression).
//
// Session ledger:
//   R1 lazy repair: serial latency chains, 5x worse. R2 (THIS structure):
//   PASSED, 1555us. R3 (DPP + LDS winner state + winner-outer sweep):
//   PASSED but 8x scratch re-reads -> 1833us. R4 (5 changes incl. global-box
//   sweep): FAILED 79.0. R5 (global-box sweep + winner-inner LDS reads):
//   FAILED identical 79.0. R6 (this source): NO SIGNAL — container infra
//   failure; kernel audited for hangs (selection consumes 1 entry/iter,
//   first selection of each pass always succeeds => progress), resubmitted.
// EMPIRICAL LAW: sweeps reading boxes from the initial private copy passed
//   3x; sweeps reading bx[j] from global failed 2x (cause not yet isolated
//   analytically). Do NOT change sweep data sourcing without a dedicated
//   single-variable round.
// R7 = R2 VERBATIM except two wave-local, provably-identical deltas:
//   (1) selection max: u64 shfl_xor butterfly -> two-phase DPP
//       (hi-max, then lo-max among hi-ties == lexicographic u64 max).
//       Consume/hbound __shfl kept verbatim (1 shuffle per iteration).
//   (2) fused sweep uses suppressed_by_fast (early zero-intersection
//       reject; bit-exact for finite inputs). Selection kill-checks keep
//       the verbatim predicate.
//
// hbound invariant (R2, passed): hidden (3rd+) boxes of a thread are
// strictly below its 2nd-best published key; consumes happen in strictly
// decreasing key order, so the SECOND consume of a pair bounds that thread's
// hidden boxes. Pass ends when pool-max <= hbound. First selection of a pass
// always succeeds -> guaranteed progress. Selection order key = (score,NA-j)
// exactly; entry-id bits sit below the unique NA-j field.
//
// __launch_bounds__(512, 1) is LOAD-BEARING.
// CRITICAL (R2 bug): winner is killed EXPLICITLY — ref IoU clips
// intersection extents to [0,1] but not areas, so self-IoU can be < 0.5.
// ---------------------------------------------------------------------------
__global__ __launch_bounds__(NMS_T, 1) void nms_kernel(
    const float4* __restrict__ boxes, const float* __restrict__ scores,
    const float* __restrict__ clsf, float* __restrict__ out)
{
    __shared__ float s_score[NA];                  // 98,256 B (own-slot reads only)
    __shared__ unsigned long long s_ckey[NPOOL];   //  8,192 B candidate keys
    __shared__ float4 s_cbox[NPOOL];               // 16,384 B candidate boxes

    const int b    = blockIdx.x;
    const int tid  = threadIdx.x;
    const int lane = tid & 63;
    const float*  sc = scores + (size_t)b * NA;
    const float4* bx = boxes  + (size_t)b * NA;
    const float*  cf = clsf   + (size_t)b * NA;
    float* ob = out + (size_t)b * TOPK * 6;

    float4 box[SLOTS];
    unsigned long long alive = 0ULL;
    #pragma unroll
    for (int s = 0; s < SLOTS; s++) {
        int j = tid + s * NMS_T;
        box[s] = make_float4(0.0f, 0.0f, 0.0f, 0.0f);
        if (j < NA) { box[s] = bx[j]; alive |= (1ULL << s); }
    }
    for (int j = tid; j < NA; j += NMS_T) s_score[j] = sc[j];
    // s_score entries are only ever read by the thread that wrote them.

    // pass-winner state — identical (uniform) across all waves every pass
    float4 wbox[KPASS]; float warea[KPASS]; float wscore[KPASS]; int wj[KPASS];
    int t = 0; bool gdone = false; int npass = 0;

    // ---- initial top-2 rescan + publish (no winners yet)
    {
        unsigned long long k1 = 0ULL, k2 = 0ULL; int j1 = -1, j2 = -1;
        #pragma unroll
        for (int s = 0; s < SLOTS; s++) {
            if (!(alive & (1ULL << s))) continue;
            int j = tid + s * NMS_T;
            unsigned long long kk =
                ((unsigned long long)__float_as_uint(s_score[j]) << 32) |
                ((unsigned long long)(unsigned)(NA - j) << 10);
            if (kk > k1)      { k2 = k1; j2 = j1; k1 = kk; j1 = j; }
            else if (kk > k2) { k2 = kk; j2 = j; }
        }
        int e0 = 2 * tid, e1 = 2 * tid + 1;
        s_ckey[CKADDR(e0)] = (j1 >= 0) ? (k1 | (unsigned long long)e0) : 1ULL;
        s_ckey[CKADDR(e1)] = (j2 >= 0) ? (k2 | (unsigned long long)e1) : 1ULL;
        if (j1 >= 0) s_cbox[e0] = bx[j1];
        if (j2 >= 0) s_cbox[e1] = bx[j2];
    }
    __syncthreads();

    while (true) {
        // ---- cache pool keys: lane L owns entries [L*16, L*16+16)
        unsigned long long ck[16];
        #pragma unroll
        for (int i = 0; i < 16; i++) ck[i] = s_ckey[(i << 6) | lane];

        // ---- selection loop (all waves redundantly; deterministic-identical)
        npass = 0;
        unsigned long long hbound = 0ULL;
        int kmax = TOPK - t; if (kmax > KPASS) kmax = KPASS;
        while (true) {
            unsigned long long lml = 0ULL;
            #pragma unroll
            for (int i = 0; i < 16; i++) if (ck[i] > lml) lml = ck[i];
            // DELTA(1): lexicographic wave-max via two-phase DPP.
            // lane contribution to phase 2 is its own max's lo iff its hi
            // equals the global hi (its max's lo dominates any other
            // same-hi entry it holds, since its max is its u64 max).
            unsigned hi = wave_umax_dpp((unsigned)(lml >> 32));
            unsigned lol = ((unsigned)(lml >> 32) == hi) ? (unsigned)lml : 0u;
            unsigned lo = wave_umax_dpp(lol);
            unsigned long long lm = ((unsigned long long)hi << 32) | lo;

            // hbound check FIRST (a hidden 3rd-best may outrank the floor-fail)
            if (!(lm > hbound)) break;                    // end pass, rescan
            float ms = __uint_as_float((unsigned)(lm >> 32));
            if (!(ms >= SCORE_FLOOR_F)) { gdone = true; break; }

            int e  = (int)(lm & 1023ULL);
            int jw = NA - (int)((lm >> 10) & 0x7FFFULL);
            float4 cb = s_cbox[e];                        // uniform broadcast
            float  ca = __fmul_rn(__fsub_rn(cb.z, cb.x), __fsub_rn(cb.w, cb.y));

            bool kill = false;
            #pragma unroll
            for (int k = 0; k < KPASS; k++)
                if (k < npass)
                    kill |= suppressed_by(cb, ca, wbox[k], warea[k]);

            // consume entry e (owner lane zeroes key; second-of-pair => hbound)
            {
                int olane = e >> 4, oi = e & 15;
                unsigned long long pk = 0ULL;
                #pragma unroll
                for (int i = 0; i < 16; i++) if (i == (oi ^ 1)) pk = ck[i];
                // pk==0: partner consumed earlier (real); pk==1: empty sentinel
                unsigned long long hb_c =
                    (lane == olane && pk == 0ULL) ? lm : 0ULL;
                unsigned long long hb = __shfl(hb_c, olane, 64);
                if (hb > hbound) hbound = hb;
                #pragma unroll
                for (int i = 0; i < 16; i++)
                    if (lane == olane && i == oi) ck[i] = 0ULL;
            }

            if (!kill) {
                #pragma unroll
                for (int k = 0; k < KPASS; k++)
                    if (k == npass) {
                        wbox[k] = cb; warea[k] = ca; wscore[k] = ms; wj[k] = jw;
                    }
                npass++;
                if (npass == kmax) break;
            }
        }

        // ---- emit winners (owner thread writes row; cls via 1 global load)
        #pragma unroll
        for (int k = 0; k < KPASS; k++) {
            if (k < npass && tid == (wj[k] & (NMS_T - 1))) {
                float* o6 = ob + (size_t)(t + k) * 6;
                o6[0] = cf[wj[k]];
                o6[1] = wscore[k];
                o6[2] = wbox[k].x; o6[3] = wbox[k].y;
                o6[4] = wbox[k].z; o6[5] = wbox[k].w;
            }
        }
        t += npass;
        if (gdone || t >= TOPK) break;

        __syncthreads();   // B1: all pool reads done before republish

        // ---- explicit winner kills BEFORE rescan (self-IoU may be < thr,
        //      and a surviving winner must not be re-offered as a candidate)
        #pragma unroll
        for (int k = 0; k < KPASS; k++)
            if (k < npass && tid == (wj[k] & (NMS_T - 1)))
                alive &= ~(1ULL << (wj[k] >> 9));

        // ---- fused: suppress vs pass winners + top-2 rescan + republish
        {
            unsigned long long k1 = 0ULL, k2 = 0ULL; int j1 = -1, j2 = -1;
            #pragma unroll
            for (int s = 0; s < SLOTS; s++) {
                if (!(alive & (1ULL << s))) continue;
                float4 v = box[s];
                float a2 = __fmul_rn(__fsub_rn(v.z, v.x), __fsub_rn(v.w, v.y));
                bool dead = false;
                #pragma unroll
                for (int k = 0; k < KPASS; k++)
                    if (k < npass)
                        dead |= suppressed_by_fast(v, a2, wbox[k], warea[k]);
                if (dead) { alive &= ~(1ULL << s); continue; }
                int j = tid + s * NMS_T;
                unsigned long long kk =
                    ((unsigned long long)__float_as_uint(s_score[j]) << 32) |
                    ((unsigned long long)(unsigned)(NA - j) << 10);
                if (kk > k1)      { k2 = k1; j2 = j1; k1 = kk; j1 = j; }
                else if (kk > k2) { k2 = kk; j2 = j; }
            }
            int e0 = 2 * tid, e1 = 2 * tid + 1;
            s_ckey[CKADDR(e0)] = (j1 >= 0) ? (k1 | (unsigned long long)e0) : 1ULL;
            s_ckey[CKADDR(e1)] = (j2 >= 0) ? (k2 | (unsigned long long)e1) : 1ULL;
            if (j1 >= 0) s_cbox[e0] = bx[j1];   // L2-resident reload
            if (j2 >= 0) s_cbox[e1] = bx[j2];
        }
        __syncthreads();   // B2: republish visible before next key-cache
    }

    for (int k = t * 6 + tid; k < TOPK * 6; k += NMS_T) ob[k] = 0.0f;
}

// ---------------------------------------------------------------------------
extern "C" void kernel_launch(void* const* d_in, const int* in_sizes, int n_in,
                              void* d_out, int out_size, void* d_ws, size_t ws_size,
                              hipStream_t stream) {
    const float* x      = (const float*)d_in[0];   // (32, 24564, 85)
    const float* anchor = (const float*)d_in[1];   // (24564, 4)
    float* out = (float*)d_out;                    // (32, 200, 6)

    char* ws = (char*)d_ws;
    const size_t boxes_bytes  = (size_t)NTOT * 16;
    const size_t scores_off   = (boxes_bytes + 255) & ~255ULL;
    const size_t scores_bytes = (size_t)NTOT * 4;
    const size_t cls_off      = (scores_off + scores_bytes + 255) & ~255ULL;

    float4* boxes  = (float4*)ws;
    float*  scores = (float*)(ws + scores_off);
    float*  clsf   = (float*)(ws + cls_off);

    decode_kernel<<<NTOT / DEC_T, DEC_T, 0, stream>>>(x, anchor, boxes, scores, clsf);
    nms_kernel<<<NB, NMS_T, 0, stream>>>(boxes, scores, clsf, out);
}

// Round 8
// 1953.314 us; speedup vs baseline: 1.1769x; 1.1320x over previous
//
#include <hip/hip_runtime.h>
#include <math.h>

// Problem constants (match reference)
#define NB   32
#define NA   24564
#define NTOT (NB * NA)          // 786048
#define NCH  85                 // 4 box deltas + 81 logits
#define TOPK 200
#define IOU_THR_F     0.5f
#define SCORE_FLOOR_F 0.01f

#define DEC_T 128               // decode block size (exact divisor of NTOT)

// ---- NMS geometry: 8 blocks per batch, 512 threads each -------------------
#define NMS_T 512
#define NSUB  8                 // blocks per batch
#define GTH   (NSUB * NMS_T)    // 4096 threads per batch
#define SL    6                 // slots/thread: ceil(24564/4096)
#define KP    16                // max winners per pass
#define NLOC  17                // candidates published per block list
#define NPOOL (2 * NMS_T)       // 1024 pool entries (top-2 per thread)
#define CKADDR(e) ((((e) & 15) << 6) | ((e) >> 4))

// global list entry: 32B {u64 key; f32 area; u32 pad; float4 box}
#define ENT_SZ      32
#define LIST_SZ     (16 + NLOC * ENT_SZ)     // 560 B (16B header: count,pad,bound)
#define BATCH_LISTS (NSUB * LIST_SZ)         // 4480 B
#define LISTS_BUF   (NB * BATCH_LISTS)       // 143,360 B per parity

// ---------------------------------------------------------------------------
// Kernel 1: decode boxes + softmax score/cls per anchor.
// Arithmetic BIT-IDENTICAL to the proven version (strict __f*_rn, exp in
// double). DO NOT alter numerics. Added: block 0 zeroes the nms inter-block
// barrier counters (runs before nms on the same stream; re-zeroed every
// launch so graph replays are safe).
// ---------------------------------------------------------------------------
__global__ __launch_bounds__(DEC_T) void decode_kernel(
    const float* __restrict__ x, const float* __restrict__ anchor,
    float4* __restrict__ boxes, float* __restrict__ scores,
    float* __restrict__ clsf, unsigned* __restrict__ arrive)
{
    __shared__ float tile[DEC_T * NCH];

    if (blockIdx.x == 0 && threadIdx.x < NB) arrive[threadIdx.x] = 0u;

    const int base = blockIdx.x * DEC_T;
    const float4* src = (const float4*)(x + (size_t)base * NCH);
    float4* dst = (float4*)tile;
    for (int k = threadIdx.x; k < DEC_T * NCH / 4; k += DEC_T) dst[k] = src[k];
    __syncthreads();

    const int g = base + threadIdx.x;
    const int i = g % NA;
    const float* row = tile + threadIdx.x * NCH;

    float ax = anchor[i * 4 + 0];
    float ay = anchor[i * 4 + 1];
    float aw = anchor[i * 4 + 2];
    float ah = anchor[i * 4 + 3];

    float d0 = row[0], d1 = row[1], d2 = row[2], d3 = row[3];
    float cx = __fadd_rn(__fdiv_rn(__fmul_rn(d0, aw), 10.0f), ax);
    float cy = __fadd_rn(__fdiv_rn(__fmul_rn(d1, ah), 10.0f), ay);
    float w = __fmul_rn((float)exp((double)__fdiv_rn(d2, 5.0f)), aw);
    float h = __fmul_rn((float)exp((double)__fdiv_rn(d3, 5.0f)), ah);
    float hw = __fmul_rn(w, 0.5f);
    float hh = __fmul_rn(h, 0.5f);
    boxes[g] = make_float4(__fsub_rn(cx, hw), __fsub_rn(cy, hh),
                           __fadd_rn(cx, hw), __fadd_rn(cy, hh));

    const float* z = row + 4;
    float m = z[0];
    #pragma unroll 9
    for (int k = 1; k < 81; k++) m = fmaxf(m, z[k]);

    double S = 0.0;
    double be = 0.0;
    float  bz = -INFINITY;
    int    bj = 0;
    for (int k = 0; k < 81; k++) {
        float zk = z[k];
        double e = exp((double)__fsub_rn(zk, m));
        S += e;
        if (k >= 1 && zk > bz) { bz = zk; be = e; bj = k - 1; }
    }
    scores[g] = (float)(be / S);
    clsf[g]   = (float)bj;
}

// ---------------------------------------------------------------------------
// IoU suppression predicate — EXACT op sequence of the reference (verbatim,
// proven R0/R2/R3/R7). v/a2 = candidate, w/a1 = winner (ref box1 = winner).
// ---------------------------------------------------------------------------
__device__ __forceinline__ bool suppressed_by(const float4 v, const float a2,
                                              const float4 w, const float a1)
{
    float xl = fmaxf(w.x, v.x);
    float xr = fminf(w.z, v.z);
    float yt = fmaxf(w.y, v.y);
    float yb = fminf(w.w, v.w);
    float cw  = fminf(fmaxf(__fsub_rn(xr, xl), 0.0f), 1.0f);
    float chh = fminf(fmaxf(__fsub_rn(yb, yt), 0.0f), 1.0f);
    float common = __fmul_rn(cw, chh);
    float denom  = __fsub_rn(__fadd_rn(a1, a2), common);
    float iou    = __fdiv_rn(common, denom);
    return !(iou < IOU_THR_F);
}

// wave64 u32-max via DPP -> readlane 63 (hardware-verified, R3/R7 passed).
__device__ __forceinline__ unsigned wave_umax_dpp(unsigned v)
{
    int x = (int)v;
    #define DPP_ST(C) { \
        int y_ = __builtin_amdgcn_update_dpp(x, x, C, 0xF, 0xF, false); \
        x = ((unsigned)y_ > (unsigned)x) ? y_ : x; }
    DPP_ST(0x111) DPP_ST(0x112) DPP_ST(0x114) DPP_ST(0x118)
    DPP_ST(0x142) DPP_ST(0x143)
    #undef DPP_ST
    return (unsigned)__builtin_amdgcn_readlane(x, 63);
}

// ---------------------------------------------------------------------------
// Kernel 2: multi-block greedy NMS. 8 blocks per batch, pass-synchronized.
// See session ledger in the round notes. Key invariants:
//  - slots/boxes in REGISTERS (box[6]) — the 3x-proven private-copy sourcing.
//  - local selection = R2/R3-proven pool+hbound machinery, kills removed.
//  - lists double-buffered by pass parity; ONE inter-block barrier per pass.
//  - global greedy is redundant + uniform across blocks (identical staged
//    bytes -> identical decisions -> no barrier divergence, no deadlock).
//  - first candidate of a pass is always accepted -> >=1 winner/pass.
//  - winner killed EXPLICITLY by index (self-IoU can be < thr).
// ---------------------------------------------------------------------------
__global__ __launch_bounds__(NMS_T, 1) void nms_kernel(
    const float4* __restrict__ boxes, const float* __restrict__ scores,
    const float* __restrict__ clsf, float* __restrict__ out,
    char* __restrict__ lists, unsigned* __restrict__ arrive)
{
    __shared__ unsigned s_cs[NPOOL];               // 4 KB key hi (score bits)
    __shared__ unsigned s_cl[NPOOL];               // 4 KB key lo ((NA-j)<<10|e)
    __shared__ float4   s_cbox[NPOOL];             // 16 KB candidate boxes
    __shared__ float4   s_stage4[BATCH_LISTS / 16];// 4.4 KB staged lists

    const int b    = blockIdx.x >> 3;
    const int sub  = blockIdx.x & 7;
    const int tid  = threadIdx.x;
    const int lane = tid & 63;
    const int gtid = sub * NMS_T + tid;            // 0..4095 within batch
    const float*  sc = scores + (size_t)b * NA;
    const float4* bx = boxes  + (size_t)b * NA;
    const float*  cf = clsf   + (size_t)b * NA;
    float* ob = out + (size_t)b * TOPK * 6;
    unsigned* arr = arrive + b;

    // ---- init: private copy (registers)
    float4 box[SL]; float a2[SL]; unsigned long long skey[SL];
    unsigned am = 0;
    #pragma unroll
    for (int s = 0; s < SL; s++) {
        int j = gtid + s * GTH;
        box[s] = make_float4(0.f, 0.f, 0.f, 0.f); a2[s] = 0.f; skey[s] = 0ULL;
        if (j < NA) {
            box[s] = bx[j];
            a2[s]  = __fmul_rn(__fsub_rn(box[s].z, box[s].x),
                               __fsub_rn(box[s].w, box[s].y));
            skey[s] = ((unsigned long long)__float_as_uint(sc[j]) << 32) |
                      ((unsigned long long)(unsigned)(NA - j) << 10);
            am |= 1u << s;
        }
    }

    unsigned long long wr0 = 0ULL, wr1 = 0ULL;     // prev-pass winner refs
    int np_prev = 0;
    int t = 0; bool gdone = false; int pass = 0;

    while (true) {
        // ---- kill phase: my slots vs prev pass winners (from staged LDS)
        if (np_prev > 0) {
            for (int k = 0; k < np_prev; k++) {
                unsigned byte = (unsigned)(((k < 8) ? (wr0 >> (8 * k))
                                                    : (wr1 >> (8 * (k - 8)))) & 0xFF);
                int wl = byte >> 5, wi = byte & 31;
                const unsigned* hdr = (const unsigned*)s_stage4 + wl * (LIST_SZ / 4);
                const unsigned* eb  = hdr + 4 + wi * (ENT_SZ / 4);
                unsigned long long wkey = *(const unsigned long long*)eb;
                float  wa = *(const float*)(eb + 2);
                float4 wb = *(const float4*)(eb + 4);
                int jw = NA - (int)((wkey >> 10) & 0x7FFFULL);
                if ((jw & (GTH - 1)) == gtid) am &= ~(1u << (jw >> 12)); // self-kill
                #pragma unroll
                for (int s = 0; s < SL; s++)
                    if (am & (1u << s))
                        if (suppressed_by(box[s], a2[s], wb, wa)) am &= ~(1u << s);
            }
        }

        // ---- rebuild top-2/thread + publish pool (R2 pattern, bx gather)
        {
            unsigned long long k1 = 0ULL, k2 = 0ULL; int s1 = -1, s2 = -1;
            #pragma unroll
            for (int s = 0; s < SL; s++) {
                if (!(am & (1u << s))) continue;
                unsigned long long kk = skey[s];
                if (kk > k1)      { k2 = k1; s2 = s1; k1 = kk; s1 = s; }
                else if (kk > k2) { k2 = kk; s2 = s; }
            }
            int e0 = 2 * tid, e1 = 2 * tid + 1;
            s_cs[CKADDR(e0)] = (s1 >= 0) ? (unsigned)(k1 >> 32) : 1u;
            s_cl[CKADDR(e0)] = (unsigned)k1 | (unsigned)e0;
            s_cs[CKADDR(e1)] = (s2 >= 0) ? (unsigned)(k2 >> 32) : 1u;
            s_cl[CKADDR(e1)] = (unsigned)k2 | (unsigned)e1;
            if (s1 >= 0) s_cbox[e0] = bx[gtid + s1 * GTH];
            if (s2 >= 0) s_cbox[e1] = bx[gtid + s2 * GTH];
        }
        __syncthreads();

        // ---- local selection (NO kills): sorted top-NLOC + bound -> global
        char* Lb = lists + (size_t)(pass & 1) * LISTS_BUF
                         + (size_t)b * BATCH_LISTS + (size_t)sub * LIST_SZ;
        {
            unsigned cs[16], cl[16];
            #pragma unroll
            for (int i = 0; i < 16; i++) {
                cs[i] = s_cs[(i << 6) | lane];
                cl[i] = s_cl[(i << 6) | lane];
            }
            int cnt = 0; unsigned long long hb = 0ULL, lastk = 0ULL, bound = 0ULL;
            while (true) {
                unsigned msl = 0u;
                #pragma unroll
                for (int i = 0; i < 16; i++) msl = (cs[i] > msl) ? cs[i] : msl;
                unsigned ms = wave_umax_dpp(msl);
                unsigned lol = 0u;
                #pragma unroll
                for (int i = 0; i < 16; i++)
                    if (cs[i] == ms) lol = (cl[i] > lol) ? cl[i] : lol;
                unsigned lo = wave_umax_dpp(lol);
                unsigned long long lm = ((unsigned long long)ms << 32) | lo;

                if (!(lm > hb)) { bound = hb; break; }
                if (!(__uint_as_float(ms) >= SCORE_FLOOR_F)) { bound = 0ULL; break; }

                int e = (int)(lo & 1023u);
                float4 cb = s_cbox[e];
                float  ca = __fmul_rn(__fsub_rn(cb.z, cb.x), __fsub_rn(cb.w, cb.y));
                if (tid == 0) {
                    char* ep = Lb + 16 + cnt * ENT_SZ;
                    *(unsigned long long*)ep = lm;
                    *(float*)(ep + 8)        = ca;
                    *(float4*)(ep + 16)      = cb;
                }
                lastk = lm;
                // consume entry e (R3-verbatim; second-of-pair raises hbound)
                int olane = e >> 4, oi = e & 15;
                unsigned pks = 0u;
                #pragma unroll
                for (int i = 0; i < 16; i++) if (i == (oi ^ 1)) pks = cs[i];
                unsigned pkol = (unsigned)__builtin_amdgcn_readlane((int)pks, olane);
                if (pkol == 0u) hb = lm;
                bool me = (lane == olane);
                #pragma unroll
                for (int i = 0; i < 16; i++) if (i == oi && me) cs[i] = 0u;
                cnt++;
                if (cnt == NLOC) { bound = lastk; break; }
            }
            if (tid == 0) {
                *(unsigned*)Lb = (unsigned)cnt;
                *(unsigned long long*)(Lb + 8) = bound;
            }
        }
        __threadfence();          // flush list writes toward coherent point
        __syncthreads();

        // ---- inter-block barrier (monotonic; one arrival per block per pass)
        if (tid == 0) {
            __hip_atomic_fetch_add(arr, 1u, __ATOMIC_ACQ_REL,
                                   __HIP_MEMORY_SCOPE_AGENT);
            unsigned tgt = (unsigned)(NSUB * (pass + 1));
            while (__hip_atomic_load(arr, __ATOMIC_ACQUIRE,
                                     __HIP_MEMORY_SCOPE_AGENT) < tgt)
                __builtin_amdgcn_s_sleep(2);
        }
        __syncthreads();

        // ---- stage my batch's 8 lists to LDS (L2-bypassing atomic loads)
        {
            const unsigned* g = (const unsigned*)(lists
                + (size_t)(pass & 1) * LISTS_BUF + (size_t)b * BATCH_LISTS);
            unsigned* dst = (unsigned*)s_stage4;
            for (int i = tid; i < BATCH_LISTS / 4; i += NMS_T)
                dst[i] = __hip_atomic_load(g + i, __ATOMIC_ACQUIRE,
                                           __HIP_MEMORY_SCOPE_AGENT);
        }
        __syncthreads();

        // ---- redundant global greedy over 8 sorted lists (uniform)
        unsigned long long cur64 = 0ULL;           // 8 cursors, 8 bits each
        unsigned long long exb = 0ULL;             // max bound of exhausted lists
        unsigned long long nwr0 = 0ULL, nwr1 = 0ULL;
        int np = 0;
        int kmaxp = TOPK - t; if (kmaxp > KP) kmaxp = KP;
        #pragma unroll
        for (int lb2 = 0; lb2 < NSUB; lb2++) {     // count==0 lists: fold bound
            const unsigned* hdr = (const unsigned*)s_stage4 + lb2 * (LIST_SZ / 4);
            if (hdr[0] == 0u) {
                unsigned long long bo = *(const unsigned long long*)(hdr + 2);
                if (bo > exb) exb = bo;
            }
        }
        while (true) {
            unsigned long long best = 0ULL; int bl = -1;
            #pragma unroll
            for (int lb2 = 0; lb2 < NSUB; lb2++) {
                const unsigned* hdr = (const unsigned*)s_stage4 + lb2 * (LIST_SZ / 4);
                unsigned c = (unsigned)((cur64 >> (8 * lb2)) & 0xFF);
                if (c < hdr[0]) {
                    unsigned long long k =
                        *(const unsigned long long*)(hdr + 4 + c * (ENT_SZ / 4));
                    if (k > best) { best = k; bl = lb2; }
                }
            }
            if (!(best > exb)) { if (best == 0ULL && exb == 0ULL) gdone = true; break; }
            float bscore = __uint_as_float((unsigned)(best >> 32));
            if (!(bscore >= SCORE_FLOOR_F)) { gdone = true; break; }

            unsigned ci = (unsigned)((cur64 >> (8 * bl)) & 0xFF);
            const unsigned* hdr = (const unsigned*)s_stage4 + bl * (LIST_SZ / 4);
            const unsigned* eb  = hdr + 4 + ci * (ENT_SZ / 4);
            float  ca2 = *(const float*)(eb + 2);
            float4 cb2 = *(const float4*)(eb + 4);

            bool kill = false;
            for (int k = 0; k < np; k++) {         // vs THIS pass's winners
                unsigned byte = (unsigned)(((k < 8) ? (nwr0 >> (8 * k))
                                                    : (nwr1 >> (8 * (k - 8)))) & 0xFF);
                int wl = byte >> 5, wi = byte & 31;
                const unsigned* wh = (const unsigned*)s_stage4 + wl * (LIST_SZ / 4);
                const unsigned* we = wh + 4 + wi * (ENT_SZ / 4);
                float  wa = *(const float*)(we + 2);
                float4 wb = *(const float4*)(we + 4);
                kill |= suppressed_by(cb2, ca2, wb, wa);
            }
            cur64 += (1ULL << (8 * bl));           // consume
            if (((cur64 >> (8 * bl)) & 0xFF) == hdr[0]) {   // just exhausted
                unsigned long long bo = *(const unsigned long long*)(hdr + 2);
                if (bo > exb) exb = bo;
            }
            if (!kill) {
                unsigned byte = (unsigned)((bl << 5) | (int)ci);
                if (np < 8) nwr0 |= ((unsigned long long)byte) << (8 * np);
                else        nwr1 |= ((unsigned long long)byte) << (8 * (np - 8));
                int jw = NA - (int)((best >> 10) & 0x7FFFULL);
                if ((jw & (GTH - 1)) == gtid) {    // owner emits the row
                    float* o6 = ob + (size_t)(t + np) * 6;
                    o6[0] = cf[jw]; o6[1] = bscore;
                    o6[2] = cb2.x; o6[3] = cb2.y; o6[4] = cb2.z; o6[5] = cb2.w;
                }
                np++;
                if (np == kmaxp) break;
            }
        }
        wr0 = nwr0; wr1 = nwr1; np_prev = np;
        t += np; pass++;
        if (gdone || t >= TOPK) break;
    }

    if (sub == 0)
        for (int k = t * 6 + tid; k < TOPK * 6; k += NMS_T) ob[k] = 0.0f;
}

// ---------------------------------------------------------------------------
extern "C" void kernel_launch(void* const* d_in, const int* in_sizes, int n_in,
                              void* d_out, int out_size, void* d_ws, size_t ws_size,
                              hipStream_t stream) {
    const float* x      = (const float*)d_in[0];   // (32, 24564, 85)
    const float* anchor = (const float*)d_in[1];   // (24564, 4)
    float* out = (float*)d_out;                    // (32, 200, 6)

    char* ws = (char*)d_ws;
    const size_t boxes_bytes  = (size_t)NTOT * 16;
    const size_t scores_off   = (boxes_bytes + 255) & ~255ULL;
    const size_t scores_bytes = (size_t)NTOT * 4;
    const size_t cls_off      = (scores_off + scores_bytes + 255) & ~255ULL;
    const size_t lists_off    = (cls_off + scores_bytes + 255) & ~255ULL;
    const size_t arrive_off   = (lists_off + 2 * (size_t)LISTS_BUF + 255) & ~255ULL;

    float4*   boxes  = (float4*)ws;
    float*    scores = (float*)(ws + scores_off);
    float*    clsf   = (float*)(ws + cls_off);
    char*     lists  = ws + lists_off;
    unsigned* arrive = (unsigned*)(ws + arrive_off);

    decode_kernel<<<NTOT / DEC_T, DEC_T, 0, stream>>>(x, anchor, boxes, scores,
                                                      clsf, arrive);
    nms_kernel<<<NB * NSUB, NMS_T, 0, stream>>>(boxes, scores, clsf, out,
                                                lists, arrive);
}

// Round 9
// 1801.252 us; speedup vs baseline: 1.2762x; 1.0844x over previous
//
#include <hip/hip_runtime.h>
#include <math.h>

// Problem constants (match reference)
#define NB   32
#define NA   24564
#define NTOT (NB * NA)          // 786048
#define NCH  85                 // 4 box deltas + 81 logits
#define TOPK 200
#define IOU_THR_F     0.5f
#define SCORE_FLOOR_F 0.01f

#define DEC_T 128               // decode block size (exact divisor of NTOT)

// ---- NMS geometry: 8 blocks per batch, 512 threads each -------------------
#define NMS_T 512
#define NSUB  8                 // blocks per batch
#define GTH   (NSUB * NMS_T)    // 4096 threads per batch
#define SL    6                 // slots/thread: ceil(24564/4096)
#define KP    32                // max winners per pass (R9: was 16)
#define NLOC  32                // candidates published per block list (R9: was 17)
#define NPOOL (2 * NMS_T)       // 1024 pool entries (top-2 per thread)
#define CKADDR(e) ((((e) & 15) << 6) | ((e) >> 4))

// global list entry: 32B {u64 key; f32 area; u32 pad; float4 box}
#define ENT_SZ      32
#define LIST_SZ     (16 + NLOC * ENT_SZ)     // 1040 B (16B header: count,pad,bound)
#define BATCH_LISTS (NSUB * LIST_SZ)         // 8320 B
#define LISTS_BUF   (NB * BATCH_LISTS)       // 266,240 B per parity

// ---------------------------------------------------------------------------
// Kernel 1: decode boxes + softmax score/cls per anchor.
// Arithmetic BIT-IDENTICAL to the proven version (strict __f*_rn, exp in
// double). DO NOT alter numerics. Block 0 zeroes the nms inter-block
// barrier counters (runs before nms on the same stream; re-zeroed every
// launch so graph replays are safe).
// ---------------------------------------------------------------------------
__global__ __launch_bounds__(DEC_T) void decode_kernel(
    const float* __restrict__ x, const float* __restrict__ anchor,
    float4* __restrict__ boxes, float* __restrict__ scores,
    float* __restrict__ clsf, unsigned* __restrict__ arrive)
{
    __shared__ float tile[DEC_T * NCH];

    if (blockIdx.x == 0 && threadIdx.x < NB) arrive[threadIdx.x] = 0u;

    const int base = blockIdx.x * DEC_T;
    const float4* src = (const float4*)(x + (size_t)base * NCH);
    float4* dst = (float4*)tile;
    for (int k = threadIdx.x; k < DEC_T * NCH / 4; k += DEC_T) dst[k] = src[k];
    __syncthreads();

    const int g = base + threadIdx.x;
    const int i = g % NA;
    const float* row = tile + threadIdx.x * NCH;

    float ax = anchor[i * 4 + 0];
    float ay = anchor[i * 4 + 1];
    float aw = anchor[i * 4 + 2];
    float ah = anchor[i * 4 + 3];

    float d0 = row[0], d1 = row[1], d2 = row[2], d3 = row[3];
    float cx = __fadd_rn(__fdiv_rn(__fmul_rn(d0, aw), 10.0f), ax);
    float cy = __fadd_rn(__fdiv_rn(__fmul_rn(d1, ah), 10.0f), ay);
    float w = __fmul_rn((float)exp((double)__fdiv_rn(d2, 5.0f)), aw);
    float h = __fmul_rn((float)exp((double)__fdiv_rn(d3, 5.0f)), ah);
    float hw = __fmul_rn(w, 0.5f);
    float hh = __fmul_rn(h, 0.5f);
    boxes[g] = make_float4(__fsub_rn(cx, hw), __fsub_rn(cy, hh),
                           __fadd_rn(cx, hw), __fadd_rn(cy, hh));

    const float* z = row + 4;
    float m = z[0];
    #pragma unroll 9
    for (int k = 1; k < 81; k++) m = fmaxf(m, z[k]);

    double S = 0.0;
    double be = 0.0;
    float  bz = -INFINITY;
    int    bj = 0;
    for (int k = 0; k < 81; k++) {
        float zk = z[k];
        double e = exp((double)__fsub_rn(zk, m));
        S += e;
        if (k >= 1 && zk > bz) { bz = zk; be = e; bj = k - 1; }
    }
    scores[g] = (float)(be / S);
    clsf[g]   = (float)bj;
}

// ---------------------------------------------------------------------------
// IoU suppression predicate — EXACT op sequence of the reference (verbatim,
// proven R0/R2/R3/R7/R8). v/a2 = candidate, w/a1 = winner (ref box1 = winner).
// ---------------------------------------------------------------------------
__device__ __forceinline__ bool suppressed_by(const float4 v, const float a2,
                                              const float4 w, const float a1)
{
    float xl = fmaxf(w.x, v.x);
    float xr = fminf(w.z, v.z);
    float yt = fmaxf(w.y, v.y);
    float yb = fminf(w.w, v.w);
    float cw  = fminf(fmaxf(__fsub_rn(xr, xl), 0.0f), 1.0f);
    float chh = fminf(fmaxf(__fsub_rn(yb, yt), 0.0f), 1.0f);
    float common = __fmul_rn(cw, chh);
    float denom  = __fsub_rn(__fadd_rn(a1, a2), common);
    float iou    = __fdiv_rn(common, denom);
    return !(iou < IOU_THR_F);
}

// wave64 u32-max via DPP -> readlane 63 (hardware-verified, R3/R7/R8 passed).
__device__ __forceinline__ unsigned wave_umax_dpp(unsigned v)
{
    int x = (int)v;
    #define DPP_ST(C) { \
        int y_ = __builtin_amdgcn_update_dpp(x, x, C, 0xF, 0xF, false); \
        x = ((unsigned)y_ > (unsigned)x) ? y_ : x; }
    DPP_ST(0x111) DPP_ST(0x112) DPP_ST(0x114) DPP_ST(0x118)
    DPP_ST(0x142) DPP_ST(0x143)
    #undef DPP_ST
    return (unsigned)__builtin_amdgcn_readlane(x, 63);
}

// ---------------------------------------------------------------------------
// Kernel 2: multi-block greedy NMS. 8 blocks per batch, pass-synchronized.
// R8 (KP=16/NLOC=17) PASSED at 1520us nms but is per-pass-overhead bound
// (VALUBusy 26%, parallel work ~2us/pass vs ~60-117us/pass wall). R9 deltas:
//  (1) KP=32, NLOC=32: halves pass count; 32-deep lists make the exhaustion
//      bound far less binding (pass runs to full KP instead of stalling).
//  (2) winner cross-pass state in LDS s_wbox/s_warea/s_wj, written by each
//      wave's lane 0 during the (redundant, uniform) merge — each wave only
//      reads its OWN writes, so no cross-wave race; replaces the 8-bit
//      packed refs (can't address 32x32) and decouples the kill phase from
//      stale staged lists.
// Everything else byte-for-byte R8: slots/boxes in REGISTERS (box[6], the
// proven private-copy sourcing); local selection = proven pool+hbound
// machinery (no kills); lists double-buffered by pass parity; ONE
// inter-block barrier per pass (monotonic counter, release add / acquire
// spin, agent-scope atomic staging loads — cross-XCD safe); merge is
// redundant+uniform across blocks (identical staged bytes -> identical
// decisions -> no divergence); first candidate of a pass always accepted ->
// >=1 winner/pass -> guaranteed progress; winner killed EXPLICITLY by index
// (self-IoU can be < thr).
// ---------------------------------------------------------------------------
__global__ __launch_bounds__(NMS_T, 1) void nms_kernel(
    const float4* __restrict__ boxes, const float* __restrict__ scores,
    const float* __restrict__ clsf, float* __restrict__ out,
    char* __restrict__ lists, unsigned* __restrict__ arrive)
{
    __shared__ unsigned s_cs[NPOOL];               // 4 KB key hi (score bits)
    __shared__ unsigned s_cl[NPOOL];               // 4 KB key lo ((NA-j)<<10|e)
    __shared__ float4   s_cbox[NPOOL];             // 16 KB candidate boxes
    __shared__ float4   s_stage4[BATCH_LISTS / 16];// 8.1 KB staged lists
    __shared__ float4   s_wbox[KP];                // pass winners (cross-pass)
    __shared__ float    s_warea[KP];
    __shared__ int      s_wj[KP];

    const int b    = blockIdx.x >> 3;
    const int sub  = blockIdx.x & 7;
    const int tid  = threadIdx.x;
    const int lane = tid & 63;
    const int gtid = sub * NMS_T + tid;            // 0..4095 within batch
    const float*  sc = scores + (size_t)b * NA;
    const float4* bx = boxes  + (size_t)b * NA;
    const float*  cf = clsf   + (size_t)b * NA;
    float* ob = out + (size_t)b * TOPK * 6;
    unsigned* arr = arrive + b;

    // ---- init: private copy (registers) — the proven sweep sourcing
    float4 box[SL]; float a2[SL]; unsigned long long skey[SL];
    unsigned am = 0;
    #pragma unroll
    for (int s = 0; s < SL; s++) {
        int j = gtid + s * GTH;
        box[s] = make_float4(0.f, 0.f, 0.f, 0.f); a2[s] = 0.f; skey[s] = 0ULL;
        if (j < NA) {
            box[s] = bx[j];
            a2[s]  = __fmul_rn(__fsub_rn(box[s].z, box[s].x),
                               __fsub_rn(box[s].w, box[s].y));
            skey[s] = ((unsigned long long)__float_as_uint(sc[j]) << 32) |
                      ((unsigned long long)(unsigned)(NA - j) << 10);
            am |= 1u << s;
        }
    }

    int np_prev = 0;
    int t = 0; bool gdone = false; int pass = 0;

    while (true) {
        // ---- kill phase: my slots vs prev pass winners (LDS, own-wave data)
        for (int k = 0; k < np_prev; k++) {
            float4 wb = s_wbox[k];
            float  wa = s_warea[k];
            int    jw = s_wj[k];
            if ((jw & (GTH - 1)) == gtid) am &= ~(1u << (jw >> 12)); // self-kill
            #pragma unroll
            for (int s = 0; s < SL; s++)
                if (am & (1u << s))
                    if (suppressed_by(box[s], a2[s], wb, wa)) am &= ~(1u << s);
        }

        // ---- rebuild top-2/thread + publish pool (proven pattern, bx gather)
        {
            unsigned long long k1 = 0ULL, k2 = 0ULL; int s1 = -1, s2 = -1;
            #pragma unroll
            for (int s = 0; s < SL; s++) {
                if (!(am & (1u << s))) continue;
                unsigned long long kk = skey[s];
                if (kk > k1)      { k2 = k1; s2 = s1; k1 = kk; s1 = s; }
                else if (kk > k2) { k2 = kk; s2 = s; }
            }
            int e0 = 2 * tid, e1 = 2 * tid + 1;
            s_cs[CKADDR(e0)] = (s1 >= 0) ? (unsigned)(k1 >> 32) : 1u;
            s_cl[CKADDR(e0)] = (unsigned)k1 | (unsigned)e0;
            s_cs[CKADDR(e1)] = (s2 >= 0) ? (unsigned)(k2 >> 32) : 1u;
            s_cl[CKADDR(e1)] = (unsigned)k2 | (unsigned)e1;
            if (s1 >= 0) s_cbox[e0] = bx[gtid + s1 * GTH];
            if (s2 >= 0) s_cbox[e1] = bx[gtid + s2 * GTH];
        }
        __syncthreads();

        // ---- local selection (NO kills): sorted top-NLOC + bound -> global
        char* Lb = lists + (size_t)(pass & 1) * LISTS_BUF
                         + (size_t)b * BATCH_LISTS + (size_t)sub * LIST_SZ;
        {
            unsigned cs[16], cl[16];
            #pragma unroll
            for (int i = 0; i < 16; i++) {
                cs[i] = s_cs[(i << 6) | lane];
                cl[i] = s_cl[(i << 6) | lane];
            }
            int cnt = 0; unsigned long long hb = 0ULL, lastk = 0ULL, bound = 0ULL;
            while (true) {
                unsigned msl = 0u;
                #pragma unroll
                for (int i = 0; i < 16; i++) msl = (cs[i] > msl) ? cs[i] : msl;
                unsigned ms = wave_umax_dpp(msl);
                unsigned lol = 0u;
                #pragma unroll
                for (int i = 0; i < 16; i++)
                    if (cs[i] == ms) lol = (cl[i] > lol) ? cl[i] : lol;
                unsigned lo = wave_umax_dpp(lol);
                unsigned long long lm = ((unsigned long long)ms << 32) | lo;

                if (!(lm > hb)) { bound = hb; break; }
                if (!(__uint_as_float(ms) >= SCORE_FLOOR_F)) { bound = 0ULL; break; }

                int e = (int)(lo & 1023u);
                float4 cb = s_cbox[e];
                float  ca = __fmul_rn(__fsub_rn(cb.z, cb.x), __fsub_rn(cb.w, cb.y));
                if (tid == 0) {
                    char* ep = Lb + 16 + cnt * ENT_SZ;
                    *(unsigned long long*)ep = lm;
                    *(float*)(ep + 8)        = ca;
                    *(float4*)(ep + 16)      = cb;
                }
                lastk = lm;
                // consume entry e (proven; second-of-pair raises hbound)
                int olane = e >> 4, oi = e & 15;
                unsigned pks = 0u;
                #pragma unroll
                for (int i = 0; i < 16; i++) if (i == (oi ^ 1)) pks = cs[i];
                unsigned pkol = (unsigned)__builtin_amdgcn_readlane((int)pks, olane);
                if (pkol == 0u) hb = lm;
                bool me = (lane == olane);
                #pragma unroll
                for (int i = 0; i < 16; i++) if (i == oi && me) cs[i] = 0u;
                cnt++;
                if (cnt == NLOC) { bound = lastk; break; }
            }
            if (tid == 0) {
                *(unsigned*)Lb = (unsigned)cnt;
                *(unsigned long long*)(Lb + 8) = bound;
            }
        }
        __threadfence();          // flush list writes toward coherent point
        __syncthreads();

        // ---- inter-block barrier (monotonic; one arrival per block per pass)
        if (tid == 0) {
            __hip_atomic_fetch_add(arr, 1u, __ATOMIC_ACQ_REL,
                                   __HIP_MEMORY_SCOPE_AGENT);
            unsigned tgt = (unsigned)(NSUB * (pass + 1));
            while (__hip_atomic_load(arr, __ATOMIC_ACQUIRE,
                                     __HIP_MEMORY_SCOPE_AGENT) < tgt)
                __builtin_amdgcn_s_sleep(2);
        }
        __syncthreads();

        // ---- stage my batch's 8 lists to LDS (cross-XCD-safe atomic loads)
        {
            const unsigned* g = (const unsigned*)(lists
                + (size_t)(pass & 1) * LISTS_BUF + (size_t)b * BATCH_LISTS);
            unsigned* dst = (unsigned*)s_stage4;
            for (int i = tid; i < BATCH_LISTS / 4; i += NMS_T)
                dst[i] = __hip_atomic_load(g + i, __ATOMIC_ACQUIRE,
                                           __HIP_MEMORY_SCOPE_AGENT);
        }
        __syncthreads();

        // ---- redundant global greedy over 8 sorted lists (uniform)
        unsigned long long cur64 = 0ULL;           // 8 cursors, 8 bits each
        unsigned long long exb = 0ULL;             // max bound of exhausted lists
        int np = 0;
        int kmaxp = TOPK - t; if (kmaxp > KP) kmaxp = KP;
        #pragma unroll
        for (int lb2 = 0; lb2 < NSUB; lb2++) {     // count==0 lists: fold bound
            const unsigned* hdr = (const unsigned*)s_stage4 + lb2 * (LIST_SZ / 4);
            if (hdr[0] == 0u) {
                unsigned long long bo = *(const unsigned long long*)(hdr + 2);
                if (bo > exb) exb = bo;
            }
        }
        while (true) {
            unsigned long long best = 0ULL; int bl = -1;
            #pragma unroll
            for (int lb2 = 0; lb2 < NSUB; lb2++) {
                const unsigned* hdr = (const unsigned*)s_stage4 + lb2 * (LIST_SZ / 4);
                unsigned c = (unsigned)((cur64 >> (8 * lb2)) & 0xFF);
                if (c < hdr[0]) {
                    unsigned long long k =
                        *(const unsigned long long*)(hdr + 4 + c * (ENT_SZ / 4));
                    if (k > best) { best = k; bl = lb2; }
                }
            }
            if (!(best > exb)) { if (best == 0ULL && exb == 0ULL) gdone = true; break; }
            float bscore = __uint_as_float((unsigned)(best >> 32));
            if (!(bscore >= SCORE_FLOOR_F)) { gdone = true; break; }

            unsigned ci = (unsigned)((cur64 >> (8 * bl)) & 0xFF);
            const unsigned* hdr = (const unsigned*)s_stage4 + bl * (LIST_SZ / 4);
            const unsigned* eb  = hdr + 4 + ci * (ENT_SZ / 4);
            float  ca2 = *(const float*)(eb + 2);
            float4 cb2 = *(const float4*)(eb + 4);

            bool kill = false;
            for (int k = 0; k < np; k++)           // vs THIS pass's winners
                kill |= suppressed_by(cb2, ca2, s_wbox[k], s_warea[k]);

            cur64 += (1ULL << (8 * bl));           // consume
            if (((cur64 >> (8 * bl)) & 0xFF) == hdr[0]) {   // just exhausted
                unsigned long long bo = *(const unsigned long long*)(hdr + 2);
                if (bo > exb) exb = bo;
            }
            if (!kill) {
                int jw = NA - (int)((best >> 10) & 0x7FFFULL);
                // each wave's lane 0 records the winner; a wave only ever
                // reads its OWN writes (merge is redundant + uniform), so
                // no cross-wave ordering is needed.
                if (lane == 0) {
                    s_wbox[np]  = cb2;
                    s_warea[np] = ca2;
                    s_wj[np]    = jw;
                }
                if ((jw & (GTH - 1)) == gtid) {    // owner emits the row
                    float* o6 = ob + (size_t)(t + np) * 6;
                    o6[0] = cf[jw]; o6[1] = bscore;
                    o6[2] = cb2.x; o6[3] = cb2.y; o6[4] = cb2.z; o6[5] = cb2.w;
                }
                np++;
                if (np == kmaxp) break;
            }
        }
        np_prev = np;
        t += np; pass++;
        if (gdone || t >= TOPK) break;
    }

    if (sub == 0)
        for (int k = t * 6 + tid; k < TOPK * 6; k += NMS_T) ob[k] = 0.0f;
}

// ---------------------------------------------------------------------------
extern "C" void kernel_launch(void* const* d_in, const int* in_sizes, int n_in,
                              void* d_out, int out_size, void* d_ws, size_t ws_size,
                              hipStream_t stream) {
    const float* x      = (const float*)d_in[0];   // (32, 24564, 85)
    const float* anchor = (const float*)d_in[1];   // (24564, 4)
    float* out = (float*)d_out;                    // (32, 200, 6)

    char* ws = (char*)d_ws;
    const size_t boxes_bytes  = (size_t)NTOT * 16;
    const size_t scores_off   = (boxes_bytes + 255) & ~255ULL;
    const size_t scores_bytes = (size_t)NTOT * 4;
    const size_t cls_off      = (scores_off + scores_bytes + 255) & ~255ULL;
    const size_t lists_off    = (cls_off + scores_bytes + 255) & ~255ULL;
    const size_t arrive_off   = (lists_off + 2 * (size_t)LISTS_BUF + 255) & ~255ULL;

    float4*   boxes  = (float4*)ws;
    float*    scores = (float*)(ws + scores_off);
    float*    clsf   = (float*)(ws + cls_off);
    char*     lists  = ws + lists_off;
    unsigned* arrive = (unsigned*)(ws + arrive_off);

    decode_kernel<<<NTOT / DEC_T, DEC_T, 0, stream>>>(x, anchor, boxes, scores,
                                                      clsf, arrive);
    nms_kernel<<<NB * NSUB, NMS_T, 0, stream>>>(boxes, scores, clsf, out,
                                                lists, arrive);
}